// Round 6
// baseline (277.246 us; speedup 1.0000x reference)
//
#include <hip/hip_runtime.h>
#include <hip/hip_fp16.h>
#include <stdint.h>

// GCN: out = relu(Ahat @ (X W1) + b1) -> relu(Ahat @ (. W2) + b2) -> @ Wfc + bfc
// Ahat = D^-1/2 (A+I) D^-1/2.
// Identity: layer(v) = dis[v] * ( sum_{e: dst=v} hs[src_e] + hs[v] ),
// hs[i] = (x[i] @ W) * dis[i].  Self-loops analytic.
//
// Cost model (R1..R23 measured):
//  - aggs: L2 random-request-rate bound (R9), ~1 L2 req/edge/layer
//    structurally irreducible (density 3.2e-4; fp8 fails absmax).
//  - R19 FAILED: LDS growth 29->41KB cost occupancy 5->3 blocks/CU (+5us).
//  - R21 WIN (-8.8us): sort was bound by random 4B recs2 global scatter ->
//    LDS-staged sort + uint4 coalesced drain.
//  - R22 WIN (-6.4us): int4/uint4 16B-lane loads on streaming paths.
//  - R23 CRASHED: deg parity invariant ("abs-idx parity == t&1") was only
//    true for the scalar scatter; R22's uint4 scatter gives element
//    parities 0,1,0,1 per thread. Copy-0 cursor overran c0v -> unwritten
//    srt slots -> garbage recs2 -> OOB hs1 reads -> GPU fault.
// R24 = R23 fixed: copy selection by ELEMENT parity (uint4: .x/.z->cnt0,
// .y/.w->cnt1; tail: t&1 since len4 even). deg[2v+(gi&1)] counts exactly
// even/odd bucket-relative positions (e0=b*CAP even => gi parity ==
// bucket-relative parity). Sort drops its count pass; partition adds 1
// fire-and-forget L2 atomic/edge. Predict sort -25..35%, partition
// +5..15%, total ~164..170us.

constexpr int F = 16;
constexpr int K_MAX = 256;           // max partition buckets (K=250 <= 256 assumed)
constexpr int BN = 400;              // nodes per bucket (dst / 400)
constexpr int PT = 4096;             // edges per partition tile (16/thread)
constexpr int NPB = 32;              // nodes per block in aggregation
constexpr unsigned int CAP = 14848;  // bucket capacity (mean 12800, +18 sigma), %4==0

__device__ __forceinline__ float2 h2f2(__half2 h) { return __half22float2(h); }
__device__ __forceinline__ unsigned int bkt400(unsigned int d) {
    return (unsigned int)(((unsigned long long)d * 167773ull) >> 26);  // exact d/400, d < 2^17
}

// ---- pass 1: deterministic tile partition, grouped by bucket ------------
// rec = (dst_local << 17) | src   (N < 2^17, dst_local < 400)
// gcur holds RELATIVE cursors (memset 0); absolute base = b*CAP + cursor.
// Drain also accumulates deg[2v + parity(gi)] (global, fire-and-forget).
__global__ void __launch_bounds__(256)
partition_kernel(const int* __restrict__ src, const int* __restrict__ dst,
                 unsigned int* __restrict__ gcur, unsigned int* __restrict__ recs,
                 unsigned int* __restrict__ deg, int E, int K) {
    __shared__ unsigned int hist[K_MAX * 4];
    __shared__ unsigned int offs[K_MAX * 4];
    __shared__ unsigned int gb[K_MAX];            // gbase[b] - bbase[b]
    __shared__ unsigned int wsum[4];
    __shared__ unsigned int drec[PT];
    __shared__ unsigned char dbuk[PT];            // bucket ids < 250 -> u8
    const int t = threadIdx.x;
    const int tile0 = blockIdx.x * PT;
    const int cnt = min(PT, E - tile0);
    const unsigned int myc = (unsigned int)(t & 3);
    for (int i = t; i < K * 4; i += 256) hist[i] = 0u;
    __syncthreads();
    unsigned int rec[16], bp[16];
#pragma unroll
    for (int k = 0; k < 4; ++k) {
        const int i = t * 4 + k * 1024;           // coalesced 16B/lane
        const int e = tile0 + i;
        if (i + 3 < cnt) {
            int4 s4 = *(const int4*)&src[e];
            int4 d4 = *(const int4*)&dst[e];
            int ss[4] = {s4.x, s4.y, s4.z, s4.w};
            int dd[4] = {d4.x, d4.y, d4.z, d4.w};
#pragma unroll
            for (int u = 0; u < 4; ++u) {
                unsigned int d = (unsigned int)dd[u];
                unsigned int s = (unsigned int)ss[u];
                unsigned int b = bkt400(d);
                rec[k * 4 + u] = ((d - b * (unsigned int)BN) << 17) | s;
                unsigned int pos = atomicAdd(&hist[b * 4 + myc], 1u);  // pos < 4096
                bp[k * 4 + u] = (b << 14) | (myc << 12) | pos;
            }
        } else {
#pragma unroll
            for (int u = 0; u < 4; ++u) {
                const int ii = i + u;
                bp[k * 4 + u] = 0xFFFFFFFFu;
                if (ii < cnt) {
                    unsigned int d = (unsigned int)dst[tile0 + ii];
                    unsigned int s = (unsigned int)src[tile0 + ii];
                    unsigned int b = bkt400(d);
                    rec[k * 4 + u] = ((d - b * (unsigned int)BN) << 17) | s;
                    unsigned int pos = atomicAdd(&hist[b * 4 + myc], 1u);
                    bp[k * 4 + u] = (b << 14) | (myc << 12) | pos;
                }
            }
        }
    }
    __syncthreads();
    // K <= 256: one bucket per thread. Wave-parallel exclusive scan of totals.
    const int lane = t & 63, wid = t >> 6;
    unsigned int tot = 0u;
    if (t < K) {
        unsigned int h0 = hist[t * 4 + 0], h1 = hist[t * 4 + 1];
        unsigned int h2 = hist[t * 4 + 2], h3 = hist[t * 4 + 3];
        tot = h0 + h1 + h2 + h3;
        offs[t * 4 + 0] = 0u;
        offs[t * 4 + 1] = h0;
        offs[t * 4 + 2] = h0 + h1;
        offs[t * 4 + 3] = h0 + h1 + h2;
    }
    unsigned int incl = tot;
#pragma unroll
    for (int o = 1; o < 64; o <<= 1) {
        unsigned int y = __shfl_up(incl, o, 64);
        if (lane >= o) incl += y;
    }
    if (lane == 63) wsum[wid] = incl;             // 4 full waves (blockDim 256)
    __syncthreads();
    if (t == 0) {
        unsigned int run = 0;
#pragma unroll
        for (int i = 0; i < 4; ++i) { unsigned int tmp = wsum[i]; wsum[i] = run; run += tmp; }
    }
    __syncthreads();
    if (t < K) {
        unsigned int bb = wsum[wid] + incl - tot; // exclusive prefix (tile-local base)
        unsigned int g = (unsigned int)t * CAP + atomicAdd(&gcur[t], tot);
        gb[t] = g - bb;
        offs[t * 4 + 0] += bb;
        offs[t * 4 + 1] += bb;
        offs[t * 4 + 2] += bb;
        offs[t * 4 + 3] += bb;
    }
    __syncthreads();
#pragma unroll
    for (int k = 0; k < 16; ++k) {
        if (bp[k] != 0xFFFFFFFFu) {
            unsigned int b = bp[k] >> 14, c = (bp[k] >> 12) & 3u, pos = bp[k] & 0xFFFu;
            unsigned int idx = offs[b * 4 + c] + pos;
            drec[idx] = rec[k];
            dbuk[idx] = (unsigned char)b;
        }
    }
    __syncthreads();
    for (int i = t; i < cnt; i += 256) {          // coalesced within runs
        unsigned int r = drec[i];
        unsigned int b = dbuk[i];
        unsigned int gi = gb[b] + (unsigned int)i;
        recs[gi] = r;
        unsigned int v = b * (unsigned int)BN + (r >> 17);
        atomicAdd(&deg[v * 2u + (gi & 1u)], 1u);  // fire-and-forget, no return
    }
}

// ---- pass 2: counting sort -> CSR + dis + packed rows + fused mv --------
// 1024 threads/block, one block per bucket (grid 250 <= 256 CUs: no tail).
// Count pass removed — degrees precomputed in deg[2v+par] (par = element
// parity within bucket). Scatter selects copy by ELEMENT parity.
__global__ void __launch_bounds__(1024)
sort_mv_kernel(const unsigned int* __restrict__ recs, const unsigned int* __restrict__ gcur,
               const unsigned int* __restrict__ deg,
               const float* __restrict__ x, const float* __restrict__ W1,
               float* __restrict__ dis, unsigned int* __restrict__ rp,
               unsigned int* __restrict__ recs2, __half* __restrict__ hs1, int N) {
    __shared__ unsigned int cnt0[BN];
    __shared__ unsigned int cnt1[BN];
    __shared__ unsigned int wsum[7];
    __shared__ float sdis[BN];
    __shared__ float ws[16][16];
    __shared__ float xs[64][17];
    __shared__ unsigned int srt[CAP];             // 59KB staged sorted bucket
    const int b = blockIdx.x;
    const int t = threadIdx.x;
    const int lane = t & 63, wid = t >> 6;
    if (t < 256) ws[t >> 4][t & 15] = W1[t];
    const unsigned int e0 = (unsigned int)b * CAP;
    const unsigned int len = gcur[b];             // bucket length
    const unsigned int len4 = len & ~3u;
    // block-scan of 400 degrees using first 7 waves (degrees from deg[])
    unsigned int c = 0, c0v = 0, xsc = 0;
    if (t < BN) {
        uint2 dd = *(const uint2*)&deg[2u * (unsigned int)(b * BN + t)];
        c0v = dd.x;                               // even-position count
        c = dd.x + dd.y;
        xsc = c;
#pragma unroll
        for (int o = 1; o < 64; o <<= 1) {
            unsigned int y = __shfl_up(xsc, o, 64);
            if (lane >= o) xsc += y;
        }
        if (lane == 63 || t == BN - 1) wsum[wid] = xsc;
    }
    __syncthreads();
    if (t == 0) {
        unsigned int run = 0;
#pragma unroll
        for (int i = 0; i < 7; ++i) { unsigned int tmp = wsum[i]; wsum[i] = run; run += tmp; }
    }
    __syncthreads();
    if (t < BN) {
        const unsigned int srel = wsum[wid] + xsc - c;         // bucket-relative excl prefix
        const int v = b * BN + t;
        const float dv = rsqrtf(1.0f + (float)c);
        sdis[t] = dv;
        if (v < N) {
            dis[v] = dv;
            rp[v] = (c << 24) | (e0 + srel);      // absolute start < 3.71M < 2^24
        }
        cnt0[t] = srel;                           // copy-0 cursor (even positions)
        cnt1[t] = srel + c0v;                     // copy-1 cursor (odd positions)
    }
    __syncthreads();
    // scatter: copy chosen by ELEMENT parity (matches deg's gi&1 counting)
    for (unsigned int i = 4u * t; i < len4; i += 4096u) {
        uint4 r4 = *(const uint4*)&recs[e0 + i];  // coalesced read (L2)
        unsigned int s0 = atomicAdd(&cnt0[r4.x >> 17], 1u);   // pos i+0 even
        srt[s0] = r4.x & 0x1FFFFu;
        unsigned int s1 = atomicAdd(&cnt1[r4.y >> 17], 1u);   // pos i+1 odd
        srt[s1] = r4.y & 0x1FFFFu;
        unsigned int s2 = atomicAdd(&cnt0[r4.z >> 17], 1u);   // pos i+2 even
        srt[s2] = r4.z & 0x1FFFFu;
        unsigned int s3 = atomicAdd(&cnt1[r4.w >> 17], 1u);   // pos i+3 odd
        srt[s3] = r4.w & 0x1FFFFu;
    }
    {   // tail: i = len4 + t (+1024k); len4 even -> parity == t&1
        unsigned int* mycnt = (t & 1) ? cnt1 : cnt0;
        for (unsigned int i = len4 + t; i < len; i += 1024u) {
            unsigned int r = recs[e0 + i];
            unsigned int slot = atomicAdd(&mycnt[r >> 17], 1u);
            srt[slot] = r & 0x1FFFFu;
        }
    }
    __syncthreads();
    // coalesced drain: 16B per thread per iter
    for (unsigned int i = 4u * t; i < len4; i += 4096u) {
        uint4 vv = *(const uint4*)&srt[i];                   // ds_read_b128
        *(uint4*)&recs2[e0 + i] = vv;                        // global_store_dwordx4
    }
    for (unsigned int i = len4 + t; i < len; i += 1024u)
        recs2[e0 + i] = srt[i];
    // ---- fused mv: hs1 for this block's 400 nodes (64 nodes/pass) -------
    const int n = t >> 4, j = t & 15;
#pragma unroll
    for (int tile = 0; tile < 7; ++tile) {
        const int loc = tile * 64 + n;
        const int node = b * BN + loc;
        __syncthreads();
        xs[n][j] = (loc < BN && node < N) ? x[(size_t)node * F + j] : 0.0f;
        __syncthreads();
        if (loc < BN && node < N) {
            float acc = 0.f;
#pragma unroll
            for (int k = 0; k < 16; ++k) acc += xs[n][k] * ws[k][j];
            hs1[(size_t)node * F + j] = __float2half(acc * sdis[loc]);
        }
    }
}

// ---- layer-1 aggregation + relu + W2 matvec (zero atomics) --------------
// 8-lane __half2 groups; NPB=32 nodes/block -> grid 3125 (~12 blocks/CU).
__global__ void __launch_bounds__(256)
agg1_kernel(const unsigned int* __restrict__ recs2, const unsigned int* __restrict__ rp,
            const __half2* __restrict__ hs1, const float* __restrict__ dis,
            const float* __restrict__ W2, const float* __restrict__ b1,
            __half* __restrict__ hs2, int N) {
    __shared__ float ws[16][16];
    __shared__ float hbf[NPB][17];
    const int t = threadIdx.x;
    ws[t >> 4][t & 15] = W2[t];
    const int j2 = t & 7;
    const int g8 = t >> 3;
    const int v0 = blockIdx.x * NPB;
    {
        const int v = v0 + g8;
        float sx = 0.f, sy = 0.f, dv = 0.f;
        if (v < N) {
            dv = dis[v];
            const unsigned int w = rp[v];
            unsigned int e = w & 0xFFFFFFu;
            const unsigned int e1 = e + (w >> 24);
            float2 s = h2f2(hs1[(size_t)v * 8 + j2]);       // self-loop term
            sx = s.x; sy = s.y;
            for (; e + 8 <= e1; e += 8) {                   // 8 independent rows
                unsigned int r0 = recs2[e + 0], r1 = recs2[e + 1];
                unsigned int r2 = recs2[e + 2], r3 = recs2[e + 3];
                unsigned int r4 = recs2[e + 4], r5 = recs2[e + 5];
                unsigned int r6 = recs2[e + 6], r7 = recs2[e + 7];
                float2 a0 = h2f2(hs1[r0 * 8 + j2]), a1 = h2f2(hs1[r1 * 8 + j2]);
                float2 a2 = h2f2(hs1[r2 * 8 + j2]), a3 = h2f2(hs1[r3 * 8 + j2]);
                float2 a4 = h2f2(hs1[r4 * 8 + j2]), a5 = h2f2(hs1[r5 * 8 + j2]);
                float2 a6 = h2f2(hs1[r6 * 8 + j2]), a7 = h2f2(hs1[r7 * 8 + j2]);
                sx += ((a0.x + a1.x) + (a2.x + a3.x)) + ((a4.x + a5.x) + (a6.x + a7.x));
                sy += ((a0.y + a1.y) + (a2.y + a3.y)) + ((a4.y + a5.y) + (a6.y + a7.y));
            }
            for (; e < e1; ++e) {
                float2 a = h2f2(hs1[recs2[e] * 8 + j2]);
                sx += a.x; sy += a.y;
            }
        }
        hbf[g8][2 * j2 + 0] = fmaxf(dv * sx + b1[2 * j2 + 0], 0.f);
        hbf[g8][2 * j2 + 1] = fmaxf(dv * sy + b1[2 * j2 + 1], 0.f);
    }
    __syncthreads();
    const int j = t & 15;
    const int g = t >> 4;
#pragma unroll
    for (int it = 0; it < 2; ++it) {
        const int n = g + 16 * it;
        const int v = v0 + n;
        if (v >= N) continue;
        float acc = 0.f;
#pragma unroll
        for (int k = 0; k < 16; ++k) acc += hbf[n][k] * ws[k][j];
        hs2[(size_t)v * F + j] = __float2half(acc * dis[v]);
    }
}

// ---- layer-2 aggregation + relu + FC head -------------------------------
__global__ void __launch_bounds__(256)
agg2_kernel(const unsigned int* __restrict__ recs2, const unsigned int* __restrict__ rp,
            const __half2* __restrict__ hs2, const float* __restrict__ dis,
            const float* __restrict__ b2, const float* __restrict__ Wfc,
            const float* __restrict__ bfc, float* __restrict__ out, int N) {
    const int t = threadIdx.x;
    const int j2 = t & 7;
    const int g8 = t >> 3;
    const int v0 = blockIdx.x * NPB;
    const float wfx = Wfc[2 * j2 + 0], wfy = Wfc[2 * j2 + 1];
    const float bbx = b2[2 * j2 + 0], bby = b2[2 * j2 + 1];
    const float bf = bfc[0];
    const int v = v0 + g8;
    if (v >= N) return;
    const unsigned int w = rp[v];
    unsigned int e = w & 0xFFFFFFu;
    const unsigned int e1 = e + (w >> 24);
    float2 s0 = h2f2(hs2[(size_t)v * 8 + j2]);
    float sx = s0.x, sy = s0.y;
    for (; e + 8 <= e1; e += 8) {
        unsigned int r0 = recs2[e + 0], r1 = recs2[e + 1];
        unsigned int r2 = recs2[e + 2], r3 = recs2[e + 3];
        unsigned int r4 = recs2[e + 4], r5 = recs2[e + 5];
        unsigned int r6 = recs2[e + 6], r7 = recs2[e + 7];
        float2 a0 = h2f2(hs2[r0 * 8 + j2]), a1 = h2f2(hs2[r1 * 8 + j2]);
        float2 a2 = h2f2(hs2[r2 * 8 + j2]), a3 = h2f2(hs2[r3 * 8 + j2]);
        float2 a4 = h2f2(hs2[r4 * 8 + j2]), a5 = h2f2(hs2[r5 * 8 + j2]);
        float2 a6 = h2f2(hs2[r6 * 8 + j2]), a7 = h2f2(hs2[r7 * 8 + j2]);
        sx += ((a0.x + a1.x) + (a2.x + a3.x)) + ((a4.x + a5.x) + (a6.x + a7.x));
        sy += ((a0.y + a1.y) + (a2.y + a3.y)) + ((a4.y + a5.y) + (a6.y + a7.y));
    }
    for (; e < e1; ++e) {
        float2 a = h2f2(hs2[recs2[e] * 8 + j2]);
        sx += a.x; sy += a.y;
    }
    const float dv = dis[v];
    float h = fmaxf(dv * sx + bbx, 0.f) * wfx + fmaxf(dv * sy + bby, 0.f) * wfy;
    h += __shfl_down(h, 4, 8);
    h += __shfl_down(h, 2, 8);
    h += __shfl_down(h, 1, 8);
    if (j2 == 0) out[v] = h + bf;
}

static inline char* align256(char* p) {
    return (char*)(((uintptr_t)p + 255) & ~(uintptr_t)255);
}

extern "C" void kernel_launch(void* const* d_in, const int* in_sizes, int n_in,
                              void* d_out, int out_size, void* d_ws, size_t ws_size,
                              hipStream_t stream) {
    const float* x   = (const float*)d_in[0];
    const int*   ei  = (const int*)d_in[1];
    const float* W1  = (const float*)d_in[2];
    const float* b1  = (const float*)d_in[3];
    const float* W2  = (const float*)d_in[4];
    const float* b2  = (const float*)d_in[5];
    const float* Wfc = (const float*)d_in[6];
    const float* bfc = (const float*)d_in[7];
    float* out = (float*)d_out;

    const int N = in_sizes[0] / F;        // 100000
    const int E = in_sizes[1] / 2;        // 3200000
    const int* src = ei;
    const int* dst = ei + E;
    const int K = (N + BN - 1) / BN;      // 250 (<= 256 assumed by partition scan)

    // 256-B-aligned layout (R2 lesson). hs1/hs2 NOT aliased with recs:
    // sort_mv writes hs1 while other blocks still read their recs.
    // gcur and deg contiguous -> one memset covers both.
    char* p = (char*)d_ws;
    float* dis = (float*)align256(p);                   p = (char*)(dis + N);
    unsigned int* gcur  = (unsigned int*)align256(p);   // 256 slots (K<=256)
    unsigned int* deg   = gcur + 256;                   // deg[2v+parity], 2N
    p = (char*)(deg + 2 * (size_t)N);
    unsigned int* rp    = (unsigned int*)align256(p);   p = (char*)(rp + N);
    unsigned int* recs2 = (unsigned int*)align256(p);   p = (char*)(recs2 + (size_t)K * CAP);
    unsigned int* recs  = (unsigned int*)align256(p);   p = (char*)(recs + (size_t)K * CAP);
    __half* hs1 = (__half*)align256(p);                 p = (char*)(hs1 + (size_t)N * F);
    __half* hs2 = (__half*)align256(p);

    const int T = 256;

    hipMemsetAsync(gcur, 0, (256 + 2 * (size_t)N) * sizeof(unsigned int), stream);
    partition_kernel<<<(E + PT - 1) / PT, T, 0, stream>>>(src, dst, gcur, recs, deg, E, K);
    sort_mv_kernel<<<K, 1024, 0, stream>>>(recs, gcur, deg, x, W1, dis, rp, recs2, hs1, N);
    agg1_kernel<<<(N + NPB - 1) / NPB, T, 0, stream>>>(recs2, rp, (const __half2*)hs1, dis, W2, b1, hs2, N);
    agg2_kernel<<<(N + NPB - 1) / NPB, T, 0, stream>>>(recs2, rp, (const __half2*)hs2, dis, b2, Wfc, bfc, out, N);
}

// Round 7
// 173.763 us; speedup vs baseline: 1.5955x; 1.5955x over previous
//
#include <hip/hip_runtime.h>
#include <hip/hip_fp16.h>
#include <stdint.h>

// GCN: out = relu(Ahat @ (X W1) + b1) -> relu(Ahat @ (. W2) + b2) -> @ Wfc + bfc
// Ahat = D^-1/2 (A+I) D^-1/2.
// Identity: layer(v) = dis[v] * ( sum_{e: dst=v} hs[src_e] + hs[v] ),
// hs[i] = (x[i] @ W) * dis[i].  Self-loops analytic.
//
// Cost model (R1..R24 measured):
//  - aggs: L2 random-request-rate bound (R9), ~1 L2 req/edge/layer
//    structurally irreducible (density 3.2e-4; fp8 fails absmax).
//  - R19 FAILED: LDS growth cost occupancy when >1 block/CU wanted.
//  - R21 WIN (-8.8us): random 4B global scatter is the expensive thing;
//    LDS-staged sort + uint4 coalesced drain.
//  - R22 WIN (-6.4us): int4/uint4 16B-lane loads on streaming paths.
//  - R24 FAILED (+103us): 3.2M fire-and-forget random global atomicAdds
//    in partition cost ~90us (~28ns/edge) — random L2 RMWs are expensive
//    whether or not the value returns. Partition 40->131us. REVERTED.
// R25: kill sort's global count-pass re-read ON-CHIP instead. Sort is
// 1 block/CU (grid 250 <= 256) so LDS is free up to ~160KB: stage raw
// bucket in LDS (raw[CAP], +59KB -> ~129KB total) during count pass,
// scatter LDS->LDS in pass B. Removes ~59KB HBM fetch/block (R13:
// cross-XCD-written lines re-read from HBM) for +1 ds_write_b128 +
// +1 ds_read_b128 per 4 edges. Copy parity: both passes use thread
// parity with identical loops (R23 mismatch impossible).
// Predict sort -15..30%, total ~165..171us.

constexpr int F = 16;
constexpr int K_MAX = 256;           // max partition buckets (K=250 <= 256 assumed)
constexpr int BN = 400;              // nodes per bucket (dst / 400)
constexpr int PT = 4096;             // edges per partition tile (16/thread)
constexpr int NPB = 32;              // nodes per block in aggregation
constexpr unsigned int CAP = 14848;  // bucket capacity (mean 12800, +18 sigma), %4==0

__device__ __forceinline__ float2 h2f2(__half2 h) { return __half22float2(h); }
__device__ __forceinline__ unsigned int bkt400(unsigned int d) {
    return (unsigned int)(((unsigned long long)d * 167773ull) >> 26);  // exact d/400, d < 2^17
}

// ---- pass 1: deterministic tile partition, grouped by bucket ------------
// rec = (dst_local << 17) | src   (N < 2^17, dst_local < 400)
// gcur holds RELATIVE cursors (memset 0); absolute base = b*CAP + cursor.
__global__ void __launch_bounds__(256)
partition_kernel(const int* __restrict__ src, const int* __restrict__ dst,
                 unsigned int* __restrict__ gcur, unsigned int* __restrict__ recs,
                 int E, int K) {
    __shared__ unsigned int hist[K_MAX * 4];
    __shared__ unsigned int offs[K_MAX * 4];
    __shared__ unsigned int gb[K_MAX];            // gbase[b] - bbase[b]
    __shared__ unsigned int wsum[4];
    __shared__ unsigned int drec[PT];
    __shared__ unsigned char dbuk[PT];            // bucket ids < 250 -> u8
    const int t = threadIdx.x;
    const int tile0 = blockIdx.x * PT;
    const int cnt = min(PT, E - tile0);
    const unsigned int myc = (unsigned int)(t & 3);
    for (int i = t; i < K * 4; i += 256) hist[i] = 0u;
    __syncthreads();
    unsigned int rec[16], bp[16];
#pragma unroll
    for (int k = 0; k < 4; ++k) {
        const int i = t * 4 + k * 1024;           // coalesced 16B/lane
        const int e = tile0 + i;
        if (i + 3 < cnt) {
            int4 s4 = *(const int4*)&src[e];
            int4 d4 = *(const int4*)&dst[e];
            int ss[4] = {s4.x, s4.y, s4.z, s4.w};
            int dd[4] = {d4.x, d4.y, d4.z, d4.w};
#pragma unroll
            for (int u = 0; u < 4; ++u) {
                unsigned int d = (unsigned int)dd[u];
                unsigned int s = (unsigned int)ss[u];
                unsigned int b = bkt400(d);
                rec[k * 4 + u] = ((d - b * (unsigned int)BN) << 17) | s;
                unsigned int pos = atomicAdd(&hist[b * 4 + myc], 1u);  // pos < 4096
                bp[k * 4 + u] = (b << 14) | (myc << 12) | pos;
            }
        } else {
#pragma unroll
            for (int u = 0; u < 4; ++u) {
                const int ii = i + u;
                bp[k * 4 + u] = 0xFFFFFFFFu;
                if (ii < cnt) {
                    unsigned int d = (unsigned int)dst[tile0 + ii];
                    unsigned int s = (unsigned int)src[tile0 + ii];
                    unsigned int b = bkt400(d);
                    rec[k * 4 + u] = ((d - b * (unsigned int)BN) << 17) | s;
                    unsigned int pos = atomicAdd(&hist[b * 4 + myc], 1u);
                    bp[k * 4 + u] = (b << 14) | (myc << 12) | pos;
                }
            }
        }
    }
    __syncthreads();
    // K <= 256: one bucket per thread. Wave-parallel exclusive scan of totals.
    const int lane = t & 63, wid = t >> 6;
    unsigned int tot = 0u;
    if (t < K) {
        unsigned int h0 = hist[t * 4 + 0], h1 = hist[t * 4 + 1];
        unsigned int h2 = hist[t * 4 + 2], h3 = hist[t * 4 + 3];
        tot = h0 + h1 + h2 + h3;
        offs[t * 4 + 0] = 0u;
        offs[t * 4 + 1] = h0;
        offs[t * 4 + 2] = h0 + h1;
        offs[t * 4 + 3] = h0 + h1 + h2;
    }
    unsigned int incl = tot;
#pragma unroll
    for (int o = 1; o < 64; o <<= 1) {
        unsigned int y = __shfl_up(incl, o, 64);
        if (lane >= o) incl += y;
    }
    if (lane == 63) wsum[wid] = incl;             // 4 full waves (blockDim 256)
    __syncthreads();
    if (t == 0) {
        unsigned int run = 0;
#pragma unroll
        for (int i = 0; i < 4; ++i) { unsigned int tmp = wsum[i]; wsum[i] = run; run += tmp; }
    }
    __syncthreads();
    if (t < K) {
        unsigned int bb = wsum[wid] + incl - tot; // exclusive prefix (tile-local base)
        unsigned int g = (unsigned int)t * CAP + atomicAdd(&gcur[t], tot);
        gb[t] = g - bb;
        offs[t * 4 + 0] += bb;
        offs[t * 4 + 1] += bb;
        offs[t * 4 + 2] += bb;
        offs[t * 4 + 3] += bb;
    }
    __syncthreads();
#pragma unroll
    for (int k = 0; k < 16; ++k) {
        if (bp[k] != 0xFFFFFFFFu) {
            unsigned int b = bp[k] >> 14, c = (bp[k] >> 12) & 3u, pos = bp[k] & 0xFFFu;
            unsigned int idx = offs[b * 4 + c] + pos;
            drec[idx] = rec[k];
            dbuk[idx] = (unsigned char)b;
        }
    }
    __syncthreads();
    for (int i = t; i < cnt; i += 256) {          // coalesced within runs
        unsigned int b = dbuk[i];
        recs[gb[b] + (unsigned int)i] = drec[i];
    }
}

// ---- pass 2: counting sort -> CSR + dis + packed rows + fused mv --------
// 1024 threads/block, one block per bucket (grid 250 <= 256 CUs: no tail,
// 1 block/CU -> large LDS is free).
// R25: single global read of recs; raw bucket staged in LDS; count from
// registers while staging; scatter LDS->LDS; coalesced uint4 drain.
__global__ void __launch_bounds__(1024)
sort_mv_kernel(const unsigned int* __restrict__ recs, const unsigned int* __restrict__ gcur,
               const float* __restrict__ x, const float* __restrict__ W1,
               float* __restrict__ dis, unsigned int* __restrict__ rp,
               unsigned int* __restrict__ recs2, __half* __restrict__ hs1, int N) {
    __shared__ unsigned int cnt0[BN];
    __shared__ unsigned int cnt1[BN];
    __shared__ unsigned int wsum[7];
    __shared__ float sdis[BN];
    __shared__ float ws[16][16];
    __shared__ float xs[64][17];
    __shared__ unsigned int srt[CAP];             // 59KB sorted bucket
    __shared__ unsigned int raw[CAP];             // 59KB raw staged bucket
    const int b = blockIdx.x;
    const int t = threadIdx.x;
    const int lane = t & 63, wid = t >> 6;
    if (t < BN) { cnt0[t] = 0u; cnt1[t] = 0u; }
    if (t < 256) ws[t >> 4][t & 15] = W1[t];
    __syncthreads();
    const unsigned int e0 = (unsigned int)b * CAP;
    const unsigned int len = gcur[b];             // bucket length
    const unsigned int len4 = len & ~3u;
    unsigned int* mycnt = (t & 1) ? cnt1 : cnt0;
    // pass A: single global read; stage raw to LDS; count
    for (unsigned int i = 4u * t; i < len4; i += 4096u) {
        uint4 r4 = *(const uint4*)&recs[e0 + i];  // global_load_dwordx4 (once)
        *(uint4*)&raw[i] = r4;                    // ds_write_b128
        atomicAdd(&mycnt[r4.x >> 17], 1u);
        atomicAdd(&mycnt[r4.y >> 17], 1u);
        atomicAdd(&mycnt[r4.z >> 17], 1u);
        atomicAdd(&mycnt[r4.w >> 17], 1u);
    }
    for (unsigned int i = len4 + t; i < len; i += 1024u) {
        unsigned int r = recs[e0 + i];
        raw[i] = r;
        atomicAdd(&mycnt[r >> 17], 1u);
    }
    __syncthreads();
    // block-scan of 400 degrees using first 7 waves
    unsigned int c = 0, c0v = 0, xsc = 0;
    if (t < BN) {
        c0v = cnt0[t];
        c = c0v + cnt1[t];
        xsc = c;
#pragma unroll
        for (int o = 1; o < 64; o <<= 1) {
            unsigned int y = __shfl_up(xsc, o, 64);
            if (lane >= o) xsc += y;
        }
        if (lane == 63 || t == BN - 1) wsum[wid] = xsc;
    }
    __syncthreads();
    if (t == 0) {
        unsigned int run = 0;
#pragma unroll
        for (int i = 0; i < 7; ++i) { unsigned int tmp = wsum[i]; wsum[i] = run; run += tmp; }
    }
    __syncthreads();
    if (t < BN) {
        const unsigned int srel = wsum[wid] + xsc - c;         // bucket-relative excl prefix
        const int v = b * BN + t;
        const float dv = rsqrtf(1.0f + (float)c);
        sdis[t] = dv;
        if (v < N) {
            dis[v] = dv;
            rp[v] = (c << 24) | (e0 + srel);      // absolute start < 3.71M < 2^24
        }
        cnt0[t] = srel;                           // copy-0 cursor
        cnt1[t] = srel + c0v;                     // copy-1 cursor
    }
    __syncthreads();
    // pass B: scatter LDS(raw) -> LDS(srt); same thread->element mapping
    // as pass A, so copy parity (t&1) matches the counted copy exactly.
    for (unsigned int i = 4u * t; i < len4; i += 4096u) {
        uint4 r4 = *(const uint4*)&raw[i];                   // ds_read_b128
        unsigned int s0 = atomicAdd(&mycnt[r4.x >> 17], 1u);
        srt[s0] = r4.x & 0x1FFFFu;
        unsigned int s1 = atomicAdd(&mycnt[r4.y >> 17], 1u);
        srt[s1] = r4.y & 0x1FFFFu;
        unsigned int s2 = atomicAdd(&mycnt[r4.z >> 17], 1u);
        srt[s2] = r4.z & 0x1FFFFu;
        unsigned int s3 = atomicAdd(&mycnt[r4.w >> 17], 1u);
        srt[s3] = r4.w & 0x1FFFFu;
    }
    for (unsigned int i = len4 + t; i < len; i += 1024u) {
        unsigned int r = raw[i];
        unsigned int slot = atomicAdd(&mycnt[r >> 17], 1u);
        srt[slot] = r & 0x1FFFFu;
    }
    __syncthreads();
    // coalesced drain: 16B per thread per iter
    for (unsigned int i = 4u * t; i < len4; i += 4096u) {
        uint4 vv = *(const uint4*)&srt[i];                   // ds_read_b128
        *(uint4*)&recs2[e0 + i] = vv;                        // global_store_dwordx4
    }
    for (unsigned int i = len4 + t; i < len; i += 1024u)
        recs2[e0 + i] = srt[i];
    // ---- fused mv: hs1 for this block's 400 nodes (64 nodes/pass) -------
    const int n = t >> 4, j = t & 15;
#pragma unroll
    for (int tile = 0; tile < 7; ++tile) {
        const int loc = tile * 64 + n;
        const int node = b * BN + loc;
        __syncthreads();
        xs[n][j] = (loc < BN && node < N) ? x[(size_t)node * F + j] : 0.0f;
        __syncthreads();
        if (loc < BN && node < N) {
            float acc = 0.f;
#pragma unroll
            for (int k = 0; k < 16; ++k) acc += xs[n][k] * ws[k][j];
            hs1[(size_t)node * F + j] = __float2half(acc * sdis[loc]);
        }
    }
}

// ---- layer-1 aggregation + relu + W2 matvec (zero atomics) --------------
// 8-lane __half2 groups; NPB=32 nodes/block -> grid 3125 (~12 blocks/CU).
__global__ void __launch_bounds__(256)
agg1_kernel(const unsigned int* __restrict__ recs2, const unsigned int* __restrict__ rp,
            const __half2* __restrict__ hs1, const float* __restrict__ dis,
            const float* __restrict__ W2, const float* __restrict__ b1,
            __half* __restrict__ hs2, int N) {
    __shared__ float ws[16][16];
    __shared__ float hbf[NPB][17];
    const int t = threadIdx.x;
    ws[t >> 4][t & 15] = W2[t];
    const int j2 = t & 7;
    const int g8 = t >> 3;
    const int v0 = blockIdx.x * NPB;
    {
        const int v = v0 + g8;
        float sx = 0.f, sy = 0.f, dv = 0.f;
        if (v < N) {
            dv = dis[v];
            const unsigned int w = rp[v];
            unsigned int e = w & 0xFFFFFFu;
            const unsigned int e1 = e + (w >> 24);
            float2 s = h2f2(hs1[(size_t)v * 8 + j2]);       // self-loop term
            sx = s.x; sy = s.y;
            for (; e + 8 <= e1; e += 8) {                   // 8 independent rows
                unsigned int r0 = recs2[e + 0], r1 = recs2[e + 1];
                unsigned int r2 = recs2[e + 2], r3 = recs2[e + 3];
                unsigned int r4 = recs2[e + 4], r5 = recs2[e + 5];
                unsigned int r6 = recs2[e + 6], r7 = recs2[e + 7];
                float2 a0 = h2f2(hs1[r0 * 8 + j2]), a1 = h2f2(hs1[r1 * 8 + j2]);
                float2 a2 = h2f2(hs1[r2 * 8 + j2]), a3 = h2f2(hs1[r3 * 8 + j2]);
                float2 a4 = h2f2(hs1[r4 * 8 + j2]), a5 = h2f2(hs1[r5 * 8 + j2]);
                float2 a6 = h2f2(hs1[r6 * 8 + j2]), a7 = h2f2(hs1[r7 * 8 + j2]);
                sx += ((a0.x + a1.x) + (a2.x + a3.x)) + ((a4.x + a5.x) + (a6.x + a7.x));
                sy += ((a0.y + a1.y) + (a2.y + a3.y)) + ((a4.y + a5.y) + (a6.y + a7.y));
            }
            for (; e < e1; ++e) {
                float2 a = h2f2(hs1[recs2[e] * 8 + j2]);
                sx += a.x; sy += a.y;
            }
        }
        hbf[g8][2 * j2 + 0] = fmaxf(dv * sx + b1[2 * j2 + 0], 0.f);
        hbf[g8][2 * j2 + 1] = fmaxf(dv * sy + b1[2 * j2 + 1], 0.f);
    }
    __syncthreads();
    const int j = t & 15;
    const int g = t >> 4;
#pragma unroll
    for (int it = 0; it < 2; ++it) {
        const int n = g + 16 * it;
        const int v = v0 + n;
        if (v >= N) continue;
        float acc = 0.f;
#pragma unroll
        for (int k = 0; k < 16; ++k) acc += hbf[n][k] * ws[k][j];
        hs2[(size_t)v * F + j] = __float2half(acc * dis[v]);
    }
}

// ---- layer-2 aggregation + relu + FC head -------------------------------
__global__ void __launch_bounds__(256)
agg2_kernel(const unsigned int* __restrict__ recs2, const unsigned int* __restrict__ rp,
            const __half2* __restrict__ hs2, const float* __restrict__ dis,
            const float* __restrict__ b2, const float* __restrict__ Wfc,
            const float* __restrict__ bfc, float* __restrict__ out, int N) {
    const int t = threadIdx.x;
    const int j2 = t & 7;
    const int g8 = t >> 3;
    const int v0 = blockIdx.x * NPB;
    const float wfx = Wfc[2 * j2 + 0], wfy = Wfc[2 * j2 + 1];
    const float bbx = b2[2 * j2 + 0], bby = b2[2 * j2 + 1];
    const float bf = bfc[0];
    const int v = v0 + g8;
    if (v >= N) return;
    const unsigned int w = rp[v];
    unsigned int e = w & 0xFFFFFFu;
    const unsigned int e1 = e + (w >> 24);
    float2 s0 = h2f2(hs2[(size_t)v * 8 + j2]);
    float sx = s0.x, sy = s0.y;
    for (; e + 8 <= e1; e += 8) {
        unsigned int r0 = recs2[e + 0], r1 = recs2[e + 1];
        unsigned int r2 = recs2[e + 2], r3 = recs2[e + 3];
        unsigned int r4 = recs2[e + 4], r5 = recs2[e + 5];
        unsigned int r6 = recs2[e + 6], r7 = recs2[e + 7];
        float2 a0 = h2f2(hs2[r0 * 8 + j2]), a1 = h2f2(hs2[r1 * 8 + j2]);
        float2 a2 = h2f2(hs2[r2 * 8 + j2]), a3 = h2f2(hs2[r3 * 8 + j2]);
        float2 a4 = h2f2(hs2[r4 * 8 + j2]), a5 = h2f2(hs2[r5 * 8 + j2]);
        float2 a6 = h2f2(hs2[r6 * 8 + j2]), a7 = h2f2(hs2[r7 * 8 + j2]);
        sx += ((a0.x + a1.x) + (a2.x + a3.x)) + ((a4.x + a5.x) + (a6.x + a7.x));
        sy += ((a0.y + a1.y) + (a2.y + a3.y)) + ((a4.y + a5.y) + (a6.y + a7.y));
    }
    for (; e < e1; ++e) {
        float2 a = h2f2(hs2[recs2[e] * 8 + j2]);
        sx += a.x; sy += a.y;
    }
    const float dv = dis[v];
    float h = fmaxf(dv * sx + bbx, 0.f) * wfx + fmaxf(dv * sy + bby, 0.f) * wfy;
    h += __shfl_down(h, 4, 8);
    h += __shfl_down(h, 2, 8);
    h += __shfl_down(h, 1, 8);
    if (j2 == 0) out[v] = h + bf;
}

static inline char* align256(char* p) {
    return (char*)(((uintptr_t)p + 255) & ~(uintptr_t)255);
}

extern "C" void kernel_launch(void* const* d_in, const int* in_sizes, int n_in,
                              void* d_out, int out_size, void* d_ws, size_t ws_size,
                              hipStream_t stream) {
    const float* x   = (const float*)d_in[0];
    const int*   ei  = (const int*)d_in[1];
    const float* W1  = (const float*)d_in[2];
    const float* b1  = (const float*)d_in[3];
    const float* W2  = (const float*)d_in[4];
    const float* b2  = (const float*)d_in[5];
    const float* Wfc = (const float*)d_in[6];
    const float* bfc = (const float*)d_in[7];
    float* out = (float*)d_out;

    const int N = in_sizes[0] / F;        // 100000
    const int E = in_sizes[1] / 2;        // 3200000
    const int* src = ei;
    const int* dst = ei + E;
    const int K = (N + BN - 1) / BN;      // 250 (<= 256 assumed by partition scan)

    // 256-B-aligned layout (R2 lesson). hs1/hs2 NOT aliased with recs:
    // sort_mv writes hs1 while other blocks still read their recs.
    char* p = (char*)d_ws;
    float* dis = (float*)align256(p);                   p = (char*)(dis + N);
    unsigned int* gcur  = (unsigned int*)align256(p);   p = (char*)(gcur + K);
    unsigned int* rp    = (unsigned int*)align256(p);   p = (char*)(rp + N);
    unsigned int* recs2 = (unsigned int*)align256(p);   p = (char*)(recs2 + (size_t)K * CAP);
    unsigned int* recs  = (unsigned int*)align256(p);   p = (char*)(recs + (size_t)K * CAP);
    __half* hs1 = (__half*)align256(p);                 p = (char*)(hs1 + (size_t)N * F);
    __half* hs2 = (__half*)align256(p);

    const int T = 256;

    hipMemsetAsync(gcur, 0, (size_t)K * sizeof(unsigned int), stream);
    partition_kernel<<<(E + PT - 1) / PT, T, 0, stream>>>(src, dst, gcur, recs, E, K);
    sort_mv_kernel<<<K, 1024, 0, stream>>>(recs, gcur, x, W1, dis, rp, recs2, hs1, N);
    agg1_kernel<<<(N + NPB - 1) / NPB, T, 0, stream>>>(recs2, rp, (const __half2*)hs1, dis, W2, b1, hs2, N);
    agg2_kernel<<<(N + NPB - 1) / NPB, T, 0, stream>>>(recs2, rp, (const __half2*)hs2, dis, b2, Wfc, bfc, out, N);
}